// Round 2
// baseline (492.117 us; speedup 1.0000x reference)
//
#include <hip/hip_runtime.h>
#include <stdint.h>

#define LOG2E 1.44269504088896340736f

typedef __attribute__((ext_vector_type(8))) __bf16 bf16x8;
typedef __attribute__((ext_vector_type(8))) short short8;
typedef __attribute__((ext_vector_type(4))) short s16x4;
typedef __attribute__((ext_vector_type(4))) float f32x4;

static __device__ __forceinline__ unsigned short f2bf(float f) {
    return __builtin_bit_cast(unsigned short, (__bf16)f);   // RNE, 1 HW cvt
}

static __device__ __forceinline__ float exp2_fast(float x) {
    float r;
    asm("v_exp_f32 %0, %1" : "=v"(r) : "v"(x));
    return r;
}

// global -> LDS direct copy, 16B per lane; LDS dest must be wave-uniform base.
static __device__ __forceinline__ void gload_lds16(const void* g, void* l) {
    __builtin_amdgcn_global_load_lds(
        (const __attribute__((address_space(1))) unsigned int*)g,
        (__attribute__((address_space(3))) unsigned int*)l, 16, 0, 0);
}

// bijective XCD swizzle (nwg % 8 == 0): consecutive work ids stay on one XCD's L2
static __device__ __forceinline__ int xcd_swz(int bid, int nwg) {
    return (bid & 7) * (nwg >> 3) + (bid >> 3);
}

// ---------------- elementwise cast fp32 -> bf16 ------------------------------
__global__ __launch_bounds__(256) void k_cast_bf16(
    const float* __restrict__ x, unsigned short* __restrict__ xb)
{
    const int base = blockIdx.x * 2048;            // floats per block
    const float4* xin = (const float4*)(x + base);
    s16x4* xo = (s16x4*)(xb + base);
#pragma unroll
    for (int i = 0; i < 2; ++i) {
        const float4 f = xin[threadIdx.x + i * 256];
        s16x4 v;
        v[0] = (short)f2bf(f.x); v[1] = (short)f2bf(f.y);
        v[2] = (short)f2bf(f.z); v[3] = (short)f2bf(f.w);
        xo[threadIdx.x + i * 256] = v;
    }
}

// ---------------- transpose + convert: src fp32 [R][C] -> dst bf16 [C][R] ----
__global__ __launch_bounds__(256) void k_transpose_bf16(
    const float* __restrict__ src, unsigned short* __restrict__ dst, int R, int C)
{
    __shared__ float t[32][33];
    const int tx = threadIdx.x, ty = threadIdx.y;
    const int c0 = blockIdx.x * 32, r0 = blockIdx.y * 32;
#pragma unroll
    for (int j = 0; j < 4; ++j)
        t[ty + j*8][tx] = src[(size_t)(r0 + ty + j*8) * C + (c0 + tx)];
    __syncthreads();
#pragma unroll
    for (int j = 0; j < 4; ++j)
        dst[(size_t)(c0 + ty + j*8) * R + (r0 + tx)] = f2bf(t[tx][ty + j*8]);
}

// ---------------- GEMM: A[M,1024]bf16 @ Bt[N,1024]^T, 128x128 tile, BK=32 ----
// global_load_lds staging both operands (m97 structure).
// MODE 0: epilogue scatters Q(scaled (1/8)*log2e)/K -> [head][s][hd] bf16,
//         V -> [head][hd][s] bf16 (transposed), bias fused.
// MODE 1: epilogue bias + fp32 store to Co.
template <int NBN, int MODE>
__global__ __launch_bounds__(256) void k_gemm_bt(
    const unsigned short* __restrict__ A, const unsigned short* __restrict__ Bt,
    const float* __restrict__ bias,
    unsigned short* __restrict__ Qo, unsigned short* __restrict__ Ko,
    unsigned short* __restrict__ Vo, float* __restrict__ Co)
{
    constexpr int K = 1024;
    constexpr int NN = NBN * 128;
    __shared__ __align__(16) short As[128 * 32];   // 8 KB, linear
    __shared__ __align__(16) short Bs[128 * 32];

    const int tid = threadIdx.x;
    const int w = tid >> 6, lane = tid & 63;
    const int lo16 = lane & 15, kg = lane >> 4;
    const int bid = xcd_swz(blockIdx.x, gridDim.x);
    const int bm = bid / NBN, bn = bid % NBN;
    const int wm = w >> 1, wn = w & 1;

    f32x4 acc[4][4] = {};

    // per-lane staging sources: chunk c = (i*4+w)*64+lane, row=c>>2, j=c&3
    const int c0 = w * 64 + lane, c1 = c0 + 256;
    const unsigned short* pA0 = A  + (size_t)(bm*128 + (c0 >> 2)) * K + (c0 & 3) * 8;
    const unsigned short* pA1 = A  + (size_t)(bm*128 + (c1 >> 2)) * K + (c1 & 3) * 8;
    const unsigned short* pB0 = Bt + (size_t)(bn*128 + (c0 >> 2)) * K + (c0 & 3) * 8;
    const unsigned short* pB1 = Bt + (size_t)(bn*128 + (c1 >> 2)) * K + (c1 & 3) * 8;

    for (int kt = 0; kt < K / 32; ++kt) {
        __syncthreads();                       // prev tile consumed
        gload_lds16(pA0, &As[w * 512]);
        gload_lds16(pA1, &As[(4 + w) * 512]);
        gload_lds16(pB0, &Bs[w * 512]);
        gload_lds16(pB1, &Bs[(4 + w) * 512]);
        pA0 += 32; pA1 += 32; pB0 += 32; pB1 += 32;
        __syncthreads();                       // staged (vmcnt drained)

        bf16x8 af[4], bff[4];
#pragma unroll
        for (int rb = 0; rb < 4; ++rb)
            af[rb] = *(const bf16x8*)&As[(wm*64 + rb*16 + lo16) * 32 + kg*8];
#pragma unroll
        for (int cb = 0; cb < 4; ++cb)
            bff[cb] = *(const bf16x8*)&Bs[(wn*64 + cb*16 + lo16) * 32 + kg*8];
#pragma unroll
        for (int rb = 0; rb < 4; ++rb)
#pragma unroll
            for (int cb = 0; cb < 4; ++cb)
                acc[rb][cb] = __builtin_amdgcn_mfma_f32_16x16x32_bf16(af[rb], bff[cb], acc[rb][cb], 0, 0, 0);
    }

    // epilogue: C/D layout col=lane&15, row=(lane>>4)*4+reg
#pragma unroll
    for (int rb = 0; rb < 4; ++rb) {
        const int m0 = bm*128 + wm*64 + rb*16 + kg*4;
#pragma unroll
        for (int cb = 0; cb < 4; ++cb) {
            const int n = bn*128 + wn*64 + cb*16 + lo16;
            const float bv = bias[n];
            if constexpr (MODE == 0) {
                const int which = n >> 10;
                const int h = (n >> 6) & 15;
                const int hd = n & 63;
                if (which == 2) {
                    const int b = m0 >> 11, s0 = m0 & 2047;
                    const int head = b*16 + h;
                    unsigned long long pv = 0;
#pragma unroll
                    for (int r = 0; r < 4; ++r)
                        pv |= (unsigned long long)f2bf(acc[rb][cb][r] + bv) << (16*r);
                    *(unsigned long long*)(Vo + ((size_t)head*64 + hd)*2048 + s0) = pv;
                } else {
                    unsigned short* P = (which == 0) ? Qo : Ko;
                    // Q: fold 1/sqrt(HD) AND log2(e) so attn uses exp2 directly
                    const float scq = (which == 0) ? (0.125f * LOG2E) : 1.0f;
#pragma unroll
                    for (int r = 0; r < 4; ++r) {
                        const int m = m0 + r;
                        const int b = m >> 11, s = m & 2047;
                        P[((size_t)(b*16 + h)*2048 + s)*64 + hd] = f2bf((acc[rb][cb][r] + bv) * scq);
                    }
                }
            } else {
                (void)Qo; (void)Ko; (void)Vo;
#pragma unroll
                for (int r = 0; r < 4; ++r)
                    Co[(size_t)(m0 + r) * NN + n] = acc[rb][cb][r] + bv;
            }
        }
    }
}

// ---------------- flash attention: per block = (head, 128-row Q tile) --------
// LDS 32KB: QP (Q tile, later per-wave P) + K + V^T, all 16B-XOR swizzled rows.
__global__ __launch_bounds__(256, 4) void k_attn(
    const unsigned short* __restrict__ Qg, const unsigned short* __restrict__ Kg,
    const unsigned short* __restrict__ Vtg, unsigned short* __restrict__ Og)
{
    __shared__ __align__(16) short QP[128 * 64];   // 16 KB: Q, then P (wave w owns rows w*32..)
    __shared__ __align__(16) short Ks[64 * 64];    // 8 KB
    __shared__ __align__(16) short Vs[64 * 64];    // 8 KB (V^T tile: row=hd, col=s)

    const int tid = threadIdx.x;
    const int w = tid >> 6, lane = tid & 63;
    const int lo16 = lane & 15, kg = lane >> 4;
    const int bid = xcd_swz(blockIdx.x, gridDim.x);
    const int head = bid >> 4, qt = bid & 15;
    const size_t hoff = (size_t)head * (2048 * 64);

    // ---- stage Q via global_load_lds; source pre-swizzled so linear LDS ==
    // swizzled layout: chunk c -> row=c>>3, stored j = (c&7), data j^(row&7)
#pragma unroll
    for (int i = 0; i < 4; ++i) {
        const int c = (i*4 + w) * 64 + lane;
        const int row = c >> 3, j = (c & 7) ^ ((c >> 3) & 7);
        gload_lds16(Qg + hoff + (size_t)(qt*128 + row)*64 + j*8, &QP[(i*4 + w) * 512]);
    }
    __syncthreads();

    bf16x8 aq[2][2];
#pragma unroll
    for (int rb = 0; rb < 2; ++rb)
#pragma unroll
        for (int ks = 0; ks < 2; ++ks) {
            const int q = w*32 + rb*16 + lo16;
            const int blk = (ks*4 + kg) ^ (q & 7);
            aq[rb][ks] = *(const bf16x8*)&QP[q*64 + blk*8];
        }

    float m_run[2][4], l_run[2][4];
#pragma unroll
    for (int rb = 0; rb < 2; ++rb)
#pragma unroll
        for (int r = 0; r < 4; ++r) { m_run[rb][r] = -1e30f; l_run[rb][r] = 0.f; }
    f32x4 acc_o[2][4] = {};

    short* Pw = QP + w * 2048;   // wave's P region == its own Q rows (done with them)

    // per-lane K/V staging sources (pre-swizzled), advanced per tile
    const int c0 = w*64 + lane, c1 = c0 + 256;
    const int r0 = c0 >> 3, j0 = (c0 & 7) ^ (r0 & 7);
    const int r1 = c1 >> 3, j1 = (c1 & 7) ^ (r1 & 7);
    const unsigned short* pK0 = Kg  + hoff + (size_t)r0*64 + j0*8;
    const unsigned short* pK1 = Kg  + hoff + (size_t)r1*64 + j1*8;
    const unsigned short* pV0 = Vtg + hoff + (size_t)r0*2048 + j0*8;
    const unsigned short* pV1 = Vtg + hoff + (size_t)r1*2048 + j1*8;

    for (int kv0 = 0; kv0 < 2048; kv0 += 64) {
        __syncthreads();                       // prev K/V tile consumed
        gload_lds16(pK0, &Ks[w * 512]);
        gload_lds16(pK1, &Ks[(4 + w) * 512]);
        gload_lds16(pV0, &Vs[w * 512]);
        gload_lds16(pV1, &Vs[(4 + w) * 512]);
        pK0 += 64*64; pK1 += 64*64; pV0 += 64; pV1 += 64;
        __syncthreads();                       // staged

        // S = Q K^T  (scale & log2e pre-folded into Q)
        f32x4 sc[2][4] = {};
#pragma unroll
        for (int ks = 0; ks < 2; ++ks) {
            bf16x8 bk[4];
#pragma unroll
            for (int cb = 0; cb < 4; ++cb) {
                const int kv = cb*16 + lo16;
                const int blk = (ks*4 + kg) ^ (kv & 7);
                bk[cb] = *(const bf16x8*)&Ks[kv*64 + blk*8];
            }
#pragma unroll
            for (int rb = 0; rb < 2; ++rb)
#pragma unroll
                for (int cb = 0; cb < 4; ++cb)
                    sc[rb][cb] = __builtin_amdgcn_mfma_f32_16x16x32_bf16(aq[rb][ks], bk[cb], sc[rb][cb], 0, 0, 0);
        }

        // online softmax: defer-max (THR=8), per-lane partial l (reduced at end)
#pragma unroll
        for (int rb = 0; rb < 2; ++rb) {
#pragma unroll
            for (int r = 0; r < 4; ++r) {
                float t = fmaxf(fmaxf(sc[rb][0][r], sc[rb][1][r]),
                                fmaxf(sc[rb][2][r], sc[rb][3][r]));
                const float mo = m_run[rb][r];
                if (__any(t > mo + 8.0f)) {
                    t = fmaxf(t, __shfl_xor(t, 1));
                    t = fmaxf(t, __shfl_xor(t, 2));
                    t = fmaxf(t, __shfl_xor(t, 4));
                    t = fmaxf(t, __shfl_xor(t, 8));
                    const float mn = fmaxf(mo, t);
                    const float fac = exp2_fast(mo - mn);
                    m_run[rb][r] = mn;
                    l_run[rb][r] *= fac;
#pragma unroll
                    for (int hb = 0; hb < 4; ++hb) acc_o[rb][hb][r] *= fac;
                }
                const float m = m_run[rb][r];
                float s = 0.f;
#pragma unroll
                for (int cb = 0; cb < 4; ++cb) {
                    const float p = exp2_fast(sc[rb][cb][r] - m);
                    sc[rb][cb][r] = p;
                    s += p;
                }
                l_run[rb][r] += s;             // lane-partial; no per-tile reduce
            }
        }

        // P -> bf16 -> wave-private LDS (swizzled rows)
#pragma unroll
        for (int rb = 0; rb < 2; ++rb)
#pragma unroll
            for (int cb = 0; cb < 4; ++cb)
#pragma unroll
                for (int r = 0; r < 4; ++r) {
                    const int q = rb*16 + kg*4 + r;
                    const int kv = cb*16 + lo16;
                    const int bo = q*128 + ((kv*2) ^ ((q & 7) << 4));
                    Pw[bo >> 1] = (short)f2bf(sc[rb][cb][r]);
                }

        // O += P V
#pragma unroll
        for (int ks = 0; ks < 2; ++ks) {
            bf16x8 ap[2], bvv[4];
#pragma unroll
            for (int rb = 0; rb < 2; ++rb) {
                const int q = rb*16 + lo16;
                const int blk = (ks*4 + kg) ^ (q & 7);
                ap[rb] = *(const bf16x8*)&Pw[q*64 + blk*8];
            }
#pragma unroll
            for (int hb = 0; hb < 4; ++hb) {
                const int hd = hb*16 + lo16;
                const int blk = (ks*4 + kg) ^ (hd & 7);
                bvv[hb] = *(const bf16x8*)&Vs[hd*64 + blk*8];
            }
#pragma unroll
            for (int rb = 0; rb < 2; ++rb)
#pragma unroll
                for (int hb = 0; hb < 4; ++hb)
                    acc_o[rb][hb] = __builtin_amdgcn_mfma_f32_16x16x32_bf16(ap[rb], bvv[hb], acc_o[rb][hb], 0, 0, 0);
        }
    }

    // epilogue: reduce l across the row's 16 lanes, normalize, store bf16
    const int b = head >> 4, h = head & 15;
#pragma unroll
    for (int rb = 0; rb < 2; ++rb)
#pragma unroll
        for (int r = 0; r < 4; ++r) {
            float l = l_run[rb][r];
            l += __shfl_xor(l, 1);
            l += __shfl_xor(l, 2);
            l += __shfl_xor(l, 4);
            l += __shfl_xor(l, 8);
            const float inv = 1.0f / l;
            const int s = qt*128 + w*32 + rb*16 + kg*4 + r;
#pragma unroll
            for (int hb = 0; hb < 4; ++hb) {
                const int hd = hb*16 + lo16;
                Og[(size_t)(b*2048 + s)*1024 + h*64 + hd] = f2bf(acc_o[rb][hb][r] * inv);
            }
        }
}

// ---------------------------------------------------------------------------
extern "C" void kernel_launch(void* const* d_in, const int* in_sizes, int n_in,
                              void* d_out, int out_size, void* d_ws, size_t ws_size,
                              hipStream_t stream)
{
    const float* x      = (const float*)d_in[0];
    const float* w_qkv  = (const float*)d_in[1];
    const float* b_qkv  = (const float*)d_in[2];
    const float* w_out  = (const float*)d_in[3];
    const float* b_out  = (const float*)d_in[4];
    float* out = (float*)d_out;

    char* ws = (char*)d_ws;
    unsigned short* wqkv_t = (unsigned short*)(ws);              // 3072x1024 bf16
    unsigned short* wout_t = (unsigned short*)(ws +  6291456);   // 1024x1024 bf16
    unsigned short* Qb     = (unsigned short*)(ws +  8388608);   // [64][2048][64] bf16
    unsigned short* Kb     = (unsigned short*)(ws + 25165824);   // [64][2048][64] bf16
    unsigned short* Vb     = (unsigned short*)(ws + 41943040);   // [64][64][2048] bf16 (V^T)
    unsigned short* AO     = (unsigned short*)(ws + 58720256);   // [8192][1024] bf16
    unsigned short* xb     = AO;  // x-as-bf16 aliases AO (disjoint lifetimes)
    // total ws use: 75,497,472 B

    k_cast_bf16<<<4096, 256, 0, stream>>>(x, xb);
    k_transpose_bf16<<<dim3(96, 32), dim3(32, 8), 0, stream>>>(w_qkv, wqkv_t, 1024, 3072);
    k_transpose_bf16<<<dim3(32, 32), dim3(32, 8), 0, stream>>>(w_out, wout_t, 1024, 1024);
    k_gemm_bt<24, 0><<<64 * 24, 256, 0, stream>>>(xb, wqkv_t, b_qkv, Qb, Kb, Vb, nullptr);
    k_attn<<<64 * 16, 256, 0, stream>>>(Qb, Kb, Vb, AO);
    k_gemm_bt<8, 1><<<64 * 8, 256, 0, stream>>>(AO, wout_t, b_out, nullptr, nullptr, nullptr, out);
}

// Round 8
// 339.694 us; speedup vs baseline: 1.4487x; 1.4487x over previous
//
#include <hip/hip_runtime.h>
#include <stdint.h>

#define LOG2E 1.44269504088896340736f

typedef __attribute__((ext_vector_type(8))) __bf16 bf16x8;
typedef __attribute__((ext_vector_type(8))) short short8;
typedef __attribute__((ext_vector_type(4))) short s16x4;
typedef __attribute__((ext_vector_type(4))) float f32x4;

static __device__ __forceinline__ unsigned short f2bf(float f) {
    return __builtin_bit_cast(unsigned short, (__bf16)f);   // RNE, 1 HW cvt
}

static __device__ __forceinline__ float exp2_fast(float x) {
    float r;
    asm("v_exp_f32 %0, %1" : "=v"(r) : "v"(x));
    return r;
}

// global -> LDS direct copy, 16B per lane; LDS dest is wave-uniform base.
static __device__ __forceinline__ void gload_lds16(const void* g, void* l) {
    __builtin_amdgcn_global_load_lds(
        (const __attribute__((address_space(1))) unsigned int*)g,
        (__attribute__((address_space(3))) unsigned int*)l, 16, 0, 0);
}

// bijective XCD swizzle (nwg % 8 == 0)
static __device__ __forceinline__ int xcd_swz(int bid, int nwg) {
    return (bid & 7) * (nwg >> 3) + (bid >> 3);
}

// ---------------- elementwise cast fp32 -> bf16 ------------------------------
__global__ __launch_bounds__(256) void k_cast_bf16(
    const float* __restrict__ x, unsigned short* __restrict__ xb)
{
    const int base = blockIdx.x * 2048;
    const float4* xin = (const float4*)(x + base);
    s16x4* xo = (s16x4*)(xb + base);
#pragma unroll
    for (int i = 0; i < 2; ++i) {
        const float4 f = xin[threadIdx.x + i * 256];
        s16x4 v;
        v[0] = (short)f2bf(f.x); v[1] = (short)f2bf(f.y);
        v[2] = (short)f2bf(f.z); v[3] = (short)f2bf(f.w);
        xo[threadIdx.x + i * 256] = v;
    }
}

// ---------------- transpose + convert: src fp32 [R][C] -> dst bf16 [C][R] ----
__global__ __launch_bounds__(256) void k_transpose_bf16(
    const float* __restrict__ src, unsigned short* __restrict__ dst, int R, int C)
{
    __shared__ float t[32][33];
    const int tx = threadIdx.x, ty = threadIdx.y;
    const int c0 = blockIdx.x * 32, r0 = blockIdx.y * 32;
#pragma unroll
    for (int j = 0; j < 4; ++j)
        t[ty + j*8][tx] = src[(size_t)(r0 + ty + j*8) * C + (c0 + tx)];
    __syncthreads();
#pragma unroll
    for (int j = 0; j < 4; ++j)
        dst[(size_t)(c0 + ty + j*8) * R + (r0 + tx)] = f2bf(t[tx][ty + j*8]);
}

// ---------------- GEMM: A[M,1024]bf16 @ Bt[N,1024]^T, 128x128 tile, BK=32 ----
// 2-phase double-buffered pipeline (T3-min): prefetch kt+1, ONE barrier/tile.
// MODE 0: epilogue scatters Q(scaled (1/8)*log2e)/K -> [head][s][hd] bf16,
//         V -> [head][hd][s] bf16 (transposed), bias fused.
// MODE 1: epilogue bias + fp32 store to Co.
template <int NBN, int MODE>
__global__ __launch_bounds__(256) void k_gemm_bt(
    const unsigned short* __restrict__ A, const unsigned short* __restrict__ Bt,
    const float* __restrict__ bias,
    unsigned short* __restrict__ Qo, unsigned short* __restrict__ Ko,
    unsigned short* __restrict__ Vo, float* __restrict__ Co)
{
    constexpr int K = 1024;
    constexpr int NT = K / 32;
    constexpr int NN = NBN * 128;
    __shared__ __align__(16) short As[2][128 * 32];   // 2 x 8 KB
    __shared__ __align__(16) short Bs[2][128 * 32];

    const int tid = threadIdx.x;
    const int w = tid >> 6, lane = tid & 63;
    const int lo16 = lane & 15, kg = lane >> 4;
    const int bid = xcd_swz(blockIdx.x, gridDim.x);
    const int bm = bid / NBN, bn = bid % NBN;
    const int wm = w >> 1, wn = w & 1;

    f32x4 acc[4][4] = {};

    const int c0 = w * 64 + lane, c1 = c0 + 256;
    const unsigned short* pA0 = A  + (size_t)(bm*128 + (c0 >> 2)) * K + (c0 & 3) * 8;
    const unsigned short* pA1 = A  + (size_t)(bm*128 + (c1 >> 2)) * K + (c1 & 3) * 8;
    const unsigned short* pB0 = Bt + (size_t)(bn*128 + (c0 >> 2)) * K + (c0 & 3) * 8;
    const unsigned short* pB1 = Bt + (size_t)(bn*128 + (c1 >> 2)) * K + (c1 & 3) * 8;

    auto STAGE = [&](int kt, int b) {
        gload_lds16(pA0 + kt*32, &As[b][w * 512]);
        gload_lds16(pA1 + kt*32, &As[b][(4 + w) * 512]);
        gload_lds16(pB0 + kt*32, &Bs[b][w * 512]);
        gload_lds16(pB1 + kt*32, &Bs[b][(4 + w) * 512]);
    };
    auto COMPUTE = [&](const short* Ab, const short* Bb) {
        bf16x8 af[4], bff[4];
#pragma unroll
        for (int rb = 0; rb < 4; ++rb)
            af[rb] = *(const bf16x8*)&Ab[(wm*64 + rb*16 + lo16) * 32 + kg*8];
#pragma unroll
        for (int cb = 0; cb < 4; ++cb)
            bff[cb] = *(const bf16x8*)&Bb[(wn*64 + cb*16 + lo16) * 32 + kg*8];
#pragma unroll
        for (int rb = 0; rb < 4; ++rb)
#pragma unroll
            for (int cb = 0; cb < 4; ++cb)
                acc[rb][cb] = __builtin_amdgcn_mfma_f32_16x16x32_bf16(af[rb], bff[cb], acc[rb][cb], 0, 0, 0);
    };

    STAGE(0, 0);
    __syncthreads();
    for (int kt = 0; kt < NT; kt += 2) {
        STAGE(kt + 1, 1);            // in flight under compute
        COMPUTE(As[0], Bs[0]);
        __syncthreads();             // drains prefetch + readers done
        if (kt + 2 < NT) STAGE(kt + 2, 0);
        COMPUTE(As[1], Bs[1]);
        __syncthreads();
    }

    // epilogue: C/D layout col=lane&15, row=(lane>>4)*4+reg
#pragma unroll
    for (int rb = 0; rb < 4; ++rb) {
        const int m0 = bm*128 + wm*64 + rb*16 + kg*4;
#pragma unroll
        for (int cb = 0; cb < 4; ++cb) {
            const int n = bn*128 + wn*64 + cb*16 + lo16;
            const float bv = bias[n];
            if constexpr (MODE == 0) {
                const int which = n >> 10;
                const int h = (n >> 6) & 15;
                const int hd = n & 63;
                if (which == 2) {
                    const int b = m0 >> 11, s0 = m0 & 2047;
                    const int head = b*16 + h;
                    unsigned long long pv = 0;
#pragma unroll
                    for (int r = 0; r < 4; ++r)
                        pv |= (unsigned long long)f2bf(acc[rb][cb][r] + bv) << (16*r);
                    *(unsigned long long*)(Vo + ((size_t)head*64 + hd)*2048 + s0) = pv;
                } else {
                    unsigned short* P = (which == 0) ? Qo : Ko;
                    const float scq = (which == 0) ? (0.125f * LOG2E) : 1.0f;
#pragma unroll
                    for (int r = 0; r < 4; ++r) {
                        const int m = m0 + r;
                        const int b = m >> 11, s = m & 2047;
                        P[((size_t)(b*16 + h)*2048 + s)*64 + hd] = f2bf((acc[rb][cb][r] + bv) * scq);
                    }
                }
            } else {
                (void)Qo; (void)Ko; (void)Vo;
#pragma unroll
                for (int r = 0; r < 4; ++r)
                    Co[(size_t)(m0 + r) * NN + n] = acc[rb][cb][r] + bv;
            }
        }
    }
}

// ---------------- flash attention: per block = (head, 128-row Q tile) --------
// 2-phase double-buffered K/V pipeline; LDS 48KB; no XCD swizzle (R1 FETCH
// evidence). Q region reused as per-wave P after frags move to registers.
__global__ __launch_bounds__(256, 4) void k_attn(
    const unsigned short* __restrict__ Qg, const unsigned short* __restrict__ Kg,
    const unsigned short* __restrict__ Vtg, unsigned short* __restrict__ Og)
{
    __shared__ __align__(16) short QP[128 * 64];     // 16 KB: Q, then per-wave P
    __shared__ __align__(16) short Ks[2][64 * 64];   // 2 x 8 KB
    __shared__ __align__(16) short Vs[2][64 * 64];   // 2 x 8 KB (V^T: row=hd)

    const int tid = threadIdx.x;
    const int w = tid >> 6, lane = tid & 63;
    const int lo16 = lane & 15, kg = lane >> 4;
    const int head = blockIdx.x >> 4, qt = blockIdx.x & 15;
    const size_t hoff = (size_t)head * (2048 * 64);

    // per-lane pre-swizzled source bases (chunk c -> row=c>>3, j=(c&7)^(row&7))
    const int c0 = w*64 + lane, c1 = c0 + 256;
    const int r0 = c0 >> 3, j0 = (c0 & 7) ^ (r0 & 7);
    const int r1 = c1 >> 3, j1 = (c1 & 7) ^ (r1 & 7);
    const unsigned short* pK0 = Kg  + hoff + (size_t)r0*64 + j0*8;
    const unsigned short* pK1 = Kg  + hoff + (size_t)r1*64 + j1*8;
    const unsigned short* pV0 = Vtg + hoff + (size_t)r0*2048 + j0*8;
    const unsigned short* pV1 = Vtg + hoff + (size_t)r1*2048 + j1*8;

    auto STAGE = [&](int t, int b) {
        gload_lds16(pK0 + (size_t)t*4096, &Ks[b][w * 512]);
        gload_lds16(pK1 + (size_t)t*4096, &Ks[b][(4 + w) * 512]);
        gload_lds16(pV0 + t*64, &Vs[b][w * 512]);
        gload_lds16(pV1 + t*64, &Vs[b][(4 + w) * 512]);
    };

    // stage Q (pre-swizzled source) + first K/V tile
#pragma unroll
    for (int i = 0; i < 4; ++i) {
        const int c = (i*4 + w) * 64 + lane;
        const int row = c >> 3, j = (c & 7) ^ (row & 7);
        gload_lds16(Qg + hoff + (size_t)(qt*128 + row)*64 + j*8, &QP[(i*4 + w) * 512]);
    }
    STAGE(0, 0);
    __syncthreads();

    bf16x8 aq[2][2];
#pragma unroll
    for (int rb = 0; rb < 2; ++rb)
#pragma unroll
        for (int ks = 0; ks < 2; ++ks) {
            const int q = w*32 + rb*16 + lo16;
            const int blk = (ks*4 + kg) ^ (q & 7);
            aq[rb][ks] = *(const bf16x8*)&QP[q*64 + blk*8];
        }

    float m_run[2][4], l_run[2][4];
#pragma unroll
    for (int rb = 0; rb < 2; ++rb)
#pragma unroll
        for (int r = 0; r < 4; ++r) { m_run[rb][r] = -1e30f; l_run[rb][r] = 0.f; }
    f32x4 acc_o[2][4] = {};

    short* Pw = QP + w * 2048;   // wave-local: own Q rows, reused for P

    auto COMPUTE = [&](const short* Kb, const short* Vb) {
        // S = Q K^T  (scale & log2e pre-folded into Q)
        f32x4 sc[2][4] = {};
#pragma unroll
        for (int ks = 0; ks < 2; ++ks) {
            bf16x8 bk[4];
#pragma unroll
            for (int cb = 0; cb < 4; ++cb) {
                const int kv = cb*16 + lo16;
                const int blk = (ks*4 + kg) ^ (kv & 7);
                bk[cb] = *(const bf16x8*)&Kb[kv*64 + blk*8];
            }
#pragma unroll
            for (int rb = 0; rb < 2; ++rb)
#pragma unroll
                for (int cb = 0; cb < 4; ++cb)
                    sc[rb][cb] = __builtin_amdgcn_mfma_f32_16x16x32_bf16(aq[rb][ks], bk[cb], sc[rb][cb], 0, 0, 0);
        }

        // online softmax: defer-max (THR=8), per-lane partial l
#pragma unroll
        for (int rb = 0; rb < 2; ++rb) {
#pragma unroll
            for (int r = 0; r < 4; ++r) {
                float t = fmaxf(fmaxf(sc[rb][0][r], sc[rb][1][r]),
                                fmaxf(sc[rb][2][r], sc[rb][3][r]));
                const float mo = m_run[rb][r];
                if (__any(t > mo + 8.0f)) {
                    t = fmaxf(t, __shfl_xor(t, 1));
                    t = fmaxf(t, __shfl_xor(t, 2));
                    t = fmaxf(t, __shfl_xor(t, 4));
                    t = fmaxf(t, __shfl_xor(t, 8));
                    const float mn = fmaxf(mo, t);
                    const float fac = exp2_fast(mo - mn);
                    m_run[rb][r] = mn;
                    l_run[rb][r] *= fac;
#pragma unroll
                    for (int hb = 0; hb < 4; ++hb) acc_o[rb][hb][r] *= fac;
                }
                const float m = m_run[rb][r];
                float s = 0.f;
#pragma unroll
                for (int cb = 0; cb < 4; ++cb) {
                    const float p = exp2_fast(sc[rb][cb][r] - m);
                    sc[rb][cb][r] = p;
                    s += p;
                }
                l_run[rb][r] += s;
            }
        }

        // P -> bf16 -> wave-private LDS (swizzled rows)
#pragma unroll
        for (int rb = 0; rb < 2; ++rb)
#pragma unroll
            for (int cb = 0; cb < 4; ++cb)
#pragma unroll
                for (int r = 0; r < 4; ++r) {
                    const int q = rb*16 + kg*4 + r;
                    const int kv = cb*16 + lo16;
                    const int bo = q*128 + ((kv*2) ^ ((q & 7) << 4));
                    Pw[bo >> 1] = (short)f2bf(sc[rb][cb][r]);
                }

        // O += P V
#pragma unroll
        for (int ks = 0; ks < 2; ++ks) {
            bf16x8 ap[2], bvv[4];
#pragma unroll
            for (int rb = 0; rb < 2; ++rb) {
                const int q = rb*16 + lo16;
                const int blk = (ks*4 + kg) ^ (q & 7);
                ap[rb] = *(const bf16x8*)&Pw[q*64 + blk*8];
            }
#pragma unroll
            for (int hb = 0; hb < 4; ++hb) {
                const int hd = hb*16 + lo16;
                const int blk = (ks*4 + kg) ^ (hd & 7);
                bvv[hb] = *(const bf16x8*)&Vb[hd*64 + blk*8];
            }
#pragma unroll
            for (int rb = 0; rb < 2; ++rb)
#pragma unroll
                for (int hb = 0; hb < 4; ++hb)
                    acc_o[rb][hb] = __builtin_amdgcn_mfma_f32_16x16x32_bf16(ap[rb], bvv[hb], acc_o[rb][hb], 0, 0, 0);
        }
    };

    for (int t = 0; t < 32; t += 2) {
        STAGE(t + 1, 1);                 // prefetch under compute
        COMPUTE(Ks[0], Vs[0]);
        __syncthreads();                 // drains prefetch + readers done
        if (t + 2 < 32) STAGE(t + 2, 0);
        COMPUTE(Ks[1], Vs[1]);
        __syncthreads();
    }

    // epilogue: reduce l across row's 16 lanes, normalize, store bf16
    const int b = head >> 4, h = head & 15;
#pragma unroll
    for (int rb = 0; rb < 2; ++rb)
#pragma unroll
        for (int r = 0; r < 4; ++r) {
            float l = l_run[rb][r];
            l += __shfl_xor(l, 1);
            l += __shfl_xor(l, 2);
            l += __shfl_xor(l, 4);
            l += __shfl_xor(l, 8);
            const float inv = 1.0f / l;
            const int s = qt*128 + w*32 + rb*16 + kg*4 + r;
#pragma unroll
            for (int hb = 0; hb < 4; ++hb) {
                const int hd = hb*16 + lo16;
                Og[(size_t)(b*2048 + s)*1024 + h*64 + hd] = f2bf(acc_o[rb][hb][r] * inv);
            }
        }
}

// ---------------------------------------------------------------------------
extern "C" void kernel_launch(void* const* d_in, const int* in_sizes, int n_in,
                              void* d_out, int out_size, void* d_ws, size_t ws_size,
                              hipStream_t stream)
{
    const float* x      = (const float*)d_in[0];
    const float* w_qkv  = (const float*)d_in[1];
    const float* b_qkv  = (const float*)d_in[2];
    const float* w_out  = (const float*)d_in[3];
    const float* b_out  = (const float*)d_in[4];
    float* out = (float*)d_out;

    char* ws = (char*)d_ws;
    unsigned short* wqkv_t = (unsigned short*)(ws);              // 3072x1024 bf16
    unsigned short* wout_t = (unsigned short*)(ws +  6291456);   // 1024x1024 bf16
    unsigned short* Qb     = (unsigned short*)(ws +  8388608);   // [64][2048][64] bf16
    unsigned short* Kb     = (unsigned short*)(ws + 25165824);   // [64][2048][64] bf16
    unsigned short* Vb     = (unsigned short*)(ws + 41943040);   // [64][64][2048] bf16 (V^T)
    unsigned short* AO     = (unsigned short*)(ws + 58720256);   // [8192][1024] bf16
    unsigned short* xb     = AO;  // x-as-bf16 aliases AO (disjoint lifetimes)

    k_cast_bf16<<<4096, 256, 0, stream>>>(x, xb);
    k_transpose_bf16<<<dim3(96, 32), dim3(32, 8), 0, stream>>>(w_qkv, wqkv_t, 1024, 3072);
    k_transpose_bf16<<<dim3(32, 32), dim3(32, 8), 0, stream>>>(w_out, wout_t, 1024, 1024);
    k_gemm_bt<24, 0><<<64 * 24, 256, 0, stream>>>(xb, wqkv_t, b_qkv, Qb, Kb, Vb, nullptr);
    k_attn<<<64 * 16, 256, 0, stream>>>(Qb, Kb, Vb, AO);
    k_gemm_bt<8, 1><<<64 * 8, 256, 0, stream>>>(AO, wout_t, b_out, nullptr, nullptr, nullptr, out);
}

// Round 9
// 317.672 us; speedup vs baseline: 1.5491x; 1.0693x over previous
//
#include <hip/hip_runtime.h>
#include <stdint.h>

#define LOG2E 1.44269504088896340736f

typedef __attribute__((ext_vector_type(8))) __bf16 bf16x8;
typedef __attribute__((ext_vector_type(8))) short short8;
typedef __attribute__((ext_vector_type(4))) short s16x4;
typedef __attribute__((ext_vector_type(4))) float f32x4;
typedef __attribute__((ext_vector_type(16))) float f32x16;

static __device__ __forceinline__ unsigned short f2bf(float f) {
    return __builtin_bit_cast(unsigned short, (__bf16)f);   // RNE, 1 HW cvt
}

static __device__ __forceinline__ float exp2_fast(float x) {
    float r;
    asm("v_exp_f32 %0, %1" : "=v"(r) : "v"(x));
    return r;
}

// global -> LDS direct copy, 16B per lane; LDS dest is wave-uniform base.
static __device__ __forceinline__ void gload_lds16(const void* g, void* l) {
    __builtin_amdgcn_global_load_lds(
        (const __attribute__((address_space(1))) unsigned int*)g,
        (__attribute__((address_space(3))) unsigned int*)l, 16, 0, 0);
}

// bijective XCD swizzle (nwg % 8 == 0)
static __device__ __forceinline__ int xcd_swz(int bid, int nwg) {
    return (bid & 7) * (nwg >> 3) + (bid >> 3);
}

// ---------------- elementwise cast fp32 -> bf16 ------------------------------
__global__ __launch_bounds__(256) void k_cast_bf16(
    const float* __restrict__ x, unsigned short* __restrict__ xb)
{
    const int base = blockIdx.x * 2048;
    const float4* xin = (const float4*)(x + base);
    s16x4* xo = (s16x4*)(xb + base);
#pragma unroll
    for (int i = 0; i < 2; ++i) {
        const float4 f = xin[threadIdx.x + i * 256];
        s16x4 v;
        v[0] = (short)f2bf(f.x); v[1] = (short)f2bf(f.y);
        v[2] = (short)f2bf(f.z); v[3] = (short)f2bf(f.w);
        xo[threadIdx.x + i * 256] = v;
    }
}

// ---------------- transpose + convert: src fp32 [R][C] -> dst bf16 [C][R] ----
__global__ __launch_bounds__(256) void k_transpose_bf16(
    const float* __restrict__ src, unsigned short* __restrict__ dst, int R, int C)
{
    __shared__ float t[32][33];
    const int tx = threadIdx.x, ty = threadIdx.y;
    const int c0 = blockIdx.x * 32, r0 = blockIdx.y * 32;
#pragma unroll
    for (int j = 0; j < 4; ++j)
        t[ty + j*8][tx] = src[(size_t)(r0 + ty + j*8) * C + (c0 + tx)];
    __syncthreads();
#pragma unroll
    for (int j = 0; j < 4; ++j)
        dst[(size_t)(c0 + ty + j*8) * R + (r0 + tx)] = f2bf(t[tx][ty + j*8]);
}

// ---------------- GEMM: A[M,1024]bf16 @ Bt[N,1024]^T, 128x128 tile, BK=32 ----
// 2-phase double-buffered pipeline. (unchanged from R8 — measured good)
template <int NBN, int MODE>
__global__ __launch_bounds__(256) void k_gemm_bt(
    const unsigned short* __restrict__ A, const unsigned short* __restrict__ Bt,
    const float* __restrict__ bias,
    unsigned short* __restrict__ Qo, unsigned short* __restrict__ Ko,
    unsigned short* __restrict__ Vo, float* __restrict__ Co)
{
    constexpr int K = 1024;
    constexpr int NT = K / 32;
    constexpr int NN = NBN * 128;
    __shared__ __align__(16) short As[2][128 * 32];
    __shared__ __align__(16) short Bs[2][128 * 32];

    const int tid = threadIdx.x;
    const int w = tid >> 6, lane = tid & 63;
    const int lo16 = lane & 15, kg = lane >> 4;
    const int bid = xcd_swz(blockIdx.x, gridDim.x);
    const int bm = bid / NBN, bn = bid % NBN;
    const int wm = w >> 1, wn = w & 1;

    f32x4 acc[4][4] = {};

    const int c0 = w * 64 + lane, c1 = c0 + 256;
    const unsigned short* pA0 = A  + (size_t)(bm*128 + (c0 >> 2)) * K + (c0 & 3) * 8;
    const unsigned short* pA1 = A  + (size_t)(bm*128 + (c1 >> 2)) * K + (c1 & 3) * 8;
    const unsigned short* pB0 = Bt + (size_t)(bn*128 + (c0 >> 2)) * K + (c0 & 3) * 8;
    const unsigned short* pB1 = Bt + (size_t)(bn*128 + (c1 >> 2)) * K + (c1 & 3) * 8;

    auto STAGE = [&](int kt, int b) {
        gload_lds16(pA0 + kt*32, &As[b][w * 512]);
        gload_lds16(pA1 + kt*32, &As[b][(4 + w) * 512]);
        gload_lds16(pB0 + kt*32, &Bs[b][w * 512]);
        gload_lds16(pB1 + kt*32, &Bs[b][(4 + w) * 512]);
    };
    auto COMPUTE = [&](const short* Ab, const short* Bb) {
        bf16x8 af[4], bff[4];
#pragma unroll
        for (int rb = 0; rb < 4; ++rb)
            af[rb] = *(const bf16x8*)&Ab[(wm*64 + rb*16 + lo16) * 32 + kg*8];
#pragma unroll
        for (int cb = 0; cb < 4; ++cb)
            bff[cb] = *(const bf16x8*)&Bb[(wn*64 + cb*16 + lo16) * 32 + kg*8];
#pragma unroll
        for (int rb = 0; rb < 4; ++rb)
#pragma unroll
            for (int cb = 0; cb < 4; ++cb)
                acc[rb][cb] = __builtin_amdgcn_mfma_f32_16x16x32_bf16(af[rb], bff[cb], acc[rb][cb], 0, 0, 0);
    };

    STAGE(0, 0);
    __syncthreads();
    for (int kt = 0; kt < NT; kt += 2) {
        STAGE(kt + 1, 1);
        COMPUTE(As[0], Bs[0]);
        __syncthreads();
        if (kt + 2 < NT) STAGE(kt + 2, 0);
        COMPUTE(As[1], Bs[1]);
        __syncthreads();
    }

#pragma unroll
    for (int rb = 0; rb < 4; ++rb) {
        const int m0 = bm*128 + wm*64 + rb*16 + kg*4;
#pragma unroll
        for (int cb = 0; cb < 4; ++cb) {
            const int n = bn*128 + wn*64 + cb*16 + lo16;
            const float bv = bias[n];
            if constexpr (MODE == 0) {
                const int which = n >> 10;
                const int h = (n >> 6) & 15;
                const int hd = n & 63;
                if (which == 2) {
                    const int b = m0 >> 11, s0 = m0 & 2047;
                    const int head = b*16 + h;
                    unsigned long long pv = 0;
#pragma unroll
                    for (int r = 0; r < 4; ++r)
                        pv |= (unsigned long long)f2bf(acc[rb][cb][r] + bv) << (16*r);
                    *(unsigned long long*)(Vo + ((size_t)head*64 + hd)*2048 + s0) = pv;
                } else {
                    unsigned short* P = (which == 0) ? Qo : Ko;
                    const float scq = (which == 0) ? (0.125f * LOG2E) : 1.0f;
#pragma unroll
                    for (int r = 0; r < 4; ++r) {
                        const int m = m0 + r;
                        const int b = m >> 11, s = m & 2047;
                        P[((size_t)(b*16 + h)*2048 + s)*64 + hd] = f2bf((acc[rb][cb][r] + bv) * scq);
                    }
                }
            } else {
                (void)Qo; (void)Ko; (void)Vo;
#pragma unroll
                for (int r = 0; r < 4; ++r)
                    Co[(size_t)(m0 + r) * NN + n] = acc[rb][cb][r] + bv;
            }
        }
    }
}

// ---------------- flash attention: 32x32 swapped-QK^T, in-register P ---------
// Per block = (head, 128-row Q tile), 4 waves x 32 q-rows. Swapped QK^T:
// sc = mfma32(K,Q) -> D[kv][q], col=lane&31=q: each lane owns ONE q-row.
// Softmax lane-local (+1 shfl_xor(32)); P assembled in-register via
// cvt_pk + shfl_xor(32) selects (T12 idea, shfl variant). Q in registers.
// LDS 32KB (K/V dbuf only) -> 4 blocks/CU.
__global__ __launch_bounds__(256, 4) void k_attn(
    const unsigned short* __restrict__ Qg, const unsigned short* __restrict__ Kg,
    const unsigned short* __restrict__ Vtg, unsigned short* __restrict__ Og)
{
    __shared__ __align__(16) short Ks[2][64 * 64];   // 2 x 8 KB
    __shared__ __align__(16) short Vs[2][64 * 64];   // 2 x 8 KB (V^T: row=hd)

    const int tid = threadIdx.x;
    const int w = tid >> 6, lane = tid & 63;
    const int l31 = lane & 31, hi = lane >> 5, s7v = l31 & 7;
    const int head = blockIdx.x >> 4, qt = blockIdx.x & 15;
    const size_t hoff = (size_t)head * (2048 * 64);

    // staging sources (pre-swizzled: chunk c -> row=c>>3, j=(c&7)^(row&7)).
    // second half (c+256) has row+32 and identical j -> constant offsets.
    const int c0 = w*64 + lane;
    const int r0 = c0 >> 3, j0 = (c0 & 7) ^ (r0 & 7);
    const unsigned short* pK0 = Kg  + hoff + (size_t)r0*64 + j0*8;
    const unsigned short* pV0 = Vtg + hoff + (size_t)r0*2048 + j0*8;

    auto STAGE = [&](int t, int b) {
        gload_lds16(pK0 + (size_t)t*4096,           &Ks[b][w * 512]);
        gload_lds16(pK0 + (size_t)t*4096 + 32*64,   &Ks[b][(4 + w) * 512]);
        gload_lds16(pV0 + t*64,                     &Vs[b][w * 512]);
        gload_lds16(pV0 + t*64 + 32*2048,           &Vs[b][(4 + w) * 512]);
    };

    // Q fragments direct to registers (B-operand: row=q=l31, k=16*kt+8*hi)
    bf16x8 qf[4];
    {
        const unsigned short* qrow = Qg + hoff + (size_t)(qt*128 + w*32 + l31) * 64;
#pragma unroll
        for (int kt = 0; kt < 4; ++kt)
            qf[kt] = *(const bf16x8*)(qrow + kt*16 + hi*8);
    }

    STAGE(0, 0);
    __syncthreads();

    float m_run = -1e30f, l_run = 0.f;
    f32x16 ao0 = {}, ao1 = {};   // O rows q=(r&3)+8*(r>>2)+4*hi, cols hd=l31 / 32+l31

    auto COMPUTE = [&](const short* Kb, const short* Vb) {
        // ---- S^T = K Q^T : D[kv][q], q = l31 per lane ----
        f32x16 s0 = {}, s1 = {};   // kvb = 0, 1
#pragma unroll
        for (int kt = 0; kt < 4; ++kt) {
            const int ch = (2*kt + hi) ^ s7v;
            const bf16x8 k0 = *(const bf16x8*)&Kb[l31*64 + ch*8];
            const bf16x8 k1 = *(const bf16x8*)&Kb[(32 + l31)*64 + ch*8];
            s0 = __builtin_amdgcn_mfma_f32_32x32x16_bf16(k0, qf[kt], s0, 0, 0, 0);
            s1 = __builtin_amdgcn_mfma_f32_32x32x16_bf16(k1, qf[kt], s1, 0, 0, 0);
        }

        // ---- online softmax, lane-local row ----
        float t = fmaxf(s0[0], s1[0]);
#pragma unroll
        for (int r = 1; r < 16; ++r) t = fmaxf(t, fmaxf(s0[r], s1[r]));
        t = fmaxf(t, __shfl_xor(t, 32));
        if (__any(t > m_run + 8.0f)) {          // defer-max gate (THR=8)
            const float mn = fmaxf(m_run, t);
            const float fac = exp2_fast(m_run - mn);
            m_run = mn; l_run *= fac;
            const int fi = __builtin_bit_cast(int, fac);
#pragma unroll
            for (int r = 0; r < 16; ++r) {      // fac[q(reg)] via bpermute (rare)
                const int qa = (r & 3) + 8*(r >> 2) + 4*hi;
                const float fr = __builtin_bit_cast(float,
                    __builtin_amdgcn_ds_bpermute(qa << 2, fi));
                ao0[r] *= fr; ao1[r] *= fr;
            }
        }
        float sum = 0.f;
#pragma unroll
        for (int r = 0; r < 16; ++r) {
            const float p0 = exp2_fast(s0[r] - m_run); s0[r] = p0;
            const float p1 = exp2_fast(s1[r] - m_run); s1[r] = p1;
            sum += p0 + p1;
        }
        sum += __shfl_xor(sum, 32);
        l_run += sum;

        // ---- pack P to bf16 pairs: pk[kvb][m*2+i] = (p[4m+2i], p[4m+2i+1]) ----
        unsigned pk0[8], pk1[8];
#pragma unroll
        for (int m = 0; m < 4; ++m)
#pragma unroll
            for (int i = 0; i < 2; ++i) {
                unsigned a, b2;
                asm("v_cvt_pk_bf16_f32 %0, %1, %2"
                    : "=v"(a) : "v"(s0[4*m + 2*i]), "v"(s0[4*m + 2*i + 1]));
                asm("v_cvt_pk_bf16_f32 %0, %1, %2"
                    : "=v"(b2) : "v"(s1[4*m + 2*i]), "v"(s1[4*m + 2*i + 1]));
                pk0[m*2 + i] = a;
                pk1[m*2 + i] = b2;
            }

        // ---- O += P V : A-frag(ks) = kv 16*(ks&1)+8*hi+0..7 (+32*(ks>>1)) ----
        // v[0..3] from hi=0 partner's pk[2*(ks&1)+hi_c], v[4..7] from hi=1's.
#define PV_STEP(KS, PK)                                                        \
        {                                                                      \
            constexpr int m0 = 2*((KS) & 1), m1 = m0 + 1;                      \
            const unsigned snd0 = hi ? PK[m0*2+0] : PK[m1*2+0];                \
            const unsigned snd1 = hi ? PK[m0*2+1] : PK[m1*2+1];                \
            const unsigned rcv0 = (unsigned)__shfl_xor((int)snd0, 32);         \
            const unsigned rcv1 = (unsigned)__shfl_xor((int)snd1, 32);         \
            const unsigned kp0 = hi ? PK[m1*2+0] : PK[m0*2+0];                 \
            const unsigned kp1 = hi ? PK[m1*2+1] : PK[m0*2+1];                 \
            uint4 fw;                                                          \
            fw.x = hi ? rcv0 : kp0;  fw.y = hi ? rcv1 : kp1;                   \
            fw.z = hi ? kp0 : rcv0;  fw.w = hi ? kp1 : rcv1;                   \
            const bf16x8 pa = __builtin_bit_cast(bf16x8, fw);                  \
            const int ch = (2*(KS) + hi) ^ s7v;                                \
            const bf16x8 v0 = *(const bf16x8*)&Vb[l31*64 + ch*8];              \
            const bf16x8 v1 = *(const bf16x8*)&Vb[(32 + l31)*64 + ch*8];       \
            ao0 = __builtin_amdgcn_mfma_f32_32x32x16_bf16(pa, v0, ao0, 0,0,0); \
            ao1 = __builtin_amdgcn_mfma_f32_32x32x16_bf16(pa, v1, ao1, 0,0,0); \
        }
        PV_STEP(0, pk0) PV_STEP(1, pk0) PV_STEP(2, pk1) PV_STEP(3, pk1)
#undef PV_STEP
    };

    for (int t = 0; t < 32; t += 2) {
        STAGE(t + 1, 1);                 // prefetch under compute
        COMPUTE(Ks[0], Vs[0]);
        __syncthreads();
        if (t + 2 < 32) STAGE(t + 2, 0);
        COMPUTE(Ks[1], Vs[1]);
        __syncthreads();
    }

    // ---- epilogue: 1/l per q via bpermute, store bf16 ----
    const int b = head >> 4, h = head & 15;
    const float inv = 1.0f / l_run;
    const int ii = __builtin_bit_cast(int, inv);
#pragma unroll
    for (int r = 0; r < 16; ++r) {
        const int qa = (r & 3) + 8*(r >> 2) + 4*hi;
        const float vr = __builtin_bit_cast(float,
            __builtin_amdgcn_ds_bpermute(qa << 2, ii));
        const int s = qt*128 + w*32 + qa;
        unsigned short* op = Og + (size_t)(b*2048 + s)*1024 + h*64;
        op[l31]      = f2bf(ao0[r] * vr);
        op[32 + l31] = f2bf(ao1[r] * vr);
    }
}

// ---------------------------------------------------------------------------
extern "C" void kernel_launch(void* const* d_in, const int* in_sizes, int n_in,
                              void* d_out, int out_size, void* d_ws, size_t ws_size,
                              hipStream_t stream)
{
    const float* x      = (const float*)d_in[0];
    const float* w_qkv  = (const float*)d_in[1];
    const float* b_qkv  = (const float*)d_in[2];
    const float* w_out  = (const float*)d_in[3];
    const float* b_out  = (const float*)d_in[4];
    float* out = (float*)d_out;

    char* ws = (char*)d_ws;
    unsigned short* wqkv_t = (unsigned short*)(ws);              // 3072x1024 bf16
    unsigned short* wout_t = (unsigned short*)(ws +  6291456);   // 1024x1024 bf16
    unsigned short* Qb     = (unsigned short*)(ws +  8388608);   // [64][2048][64] bf16
    unsigned short* Kb     = (unsigned short*)(ws + 25165824);   // [64][2048][64] bf16
    unsigned short* Vb     = (unsigned short*)(ws + 41943040);   // [64][64][2048] bf16 (V^T)
    unsigned short* AO     = (unsigned short*)(ws + 58720256);   // [8192][1024] bf16
    unsigned short* xb     = AO;  // x-as-bf16 aliases AO (disjoint lifetimes)

    k_cast_bf16<<<4096, 256, 0, stream>>>(x, xb);
    k_transpose_bf16<<<dim3(96, 32), dim3(32, 8), 0, stream>>>(w_qkv, wqkv_t, 1024, 3072);
    k_transpose_bf16<<<dim3(32, 32), dim3(32, 8), 0, stream>>>(w_out, wout_t, 1024, 1024);
    k_gemm_bt<24, 0><<<64 * 24, 256, 0, stream>>>(xb, wqkv_t, b_qkv, Qb, Kb, Vb, nullptr);
    k_attn<<<64 * 16, 256, 0, stream>>>(Qb, Kb, Vb, AO);
    k_gemm_bt<8, 1><<<64 * 8, 256, 0, stream>>>(AO, wout_t, b_out, nullptr, nullptr, nullptr, out);
}